// Round 14
// baseline (92.345 us; speedup 1.0000x reference)
//
#include <hip/hip_runtime.h>

#define HDIM 256   // output hidden dim
#define KDIM 512   // 2*HDIM (concat)
#define ROWS 16    // batch rows per mfma block (one MFMA M-tile)
#define XBPAD 8    // xbf row stride 520 shorts (1040 B, 16B-aligned)
#define LN_EPS 1e-5f
#define COPY_BLOCKS 1024

typedef __attribute__((ext_vector_type(8))) short bf16x8;
typedef __attribute__((ext_vector_type(4))) float f32x4;

static __device__ __forceinline__ unsigned short f2bf(float f) {
    union { float f; unsigned u; } v; v.f = f;
    unsigned r = v.u + 0x7FFF + ((v.u >> 16) & 1);   // RNE
    return (unsigned short)(r >> 16);
}

// K1: pack W2 -> bf16 B-fragments (round-7 probe-verified layout) + winner init.
// fragment tid = ct*1024 + ks*64 + l; elem j of lane l =
//   W2[ks*32 + (l>>4)*8 + j][ct*16 + (l&15)]
__global__ __launch_bounds__(256) void prep_init_kernel(
    const float* __restrict__ W2, unsigned short* __restrict__ W2f,
    int* __restrict__ winner, const int* __restrict__ node_batch, int B)
{
    int tid = blockIdx.x * 256 + threadIdx.x;      // 0..16383
    for (int i = tid; i < B; i += 64 * 256) winner[node_batch[i]] = -1;
    if (tid >= 16 * 16 * 64) return;
    int l  = tid & 63;
    int ks = (tid >> 6) & 15;
    int ct = tid >> 10;
    int col = ct * 16 + (l & 15);
    int k0  = ks * 32 + (l >> 4) * 8;
    unsigned short pk[8];
    #pragma unroll
    for (int j = 0; j < 8; ++j)
        pk[j] = f2bf(W2[(size_t)(k0 + j) * HDIM + col]);
    *(uint4*)&W2f[(size_t)tid * 8] = *(uint4*)pk;
}

// K2: fused producer. Even blocks: NONTEMPORAL copy of hidden2 FIRST HALF ->
// out_tab + winner atomicMax (atomicMax must finish before K3 reads winner;
// kernel boundary guarantees it). Odd blocks: gather+mean -> bf16 LDS ->
// MFMA (probe-verified H1 config) -> raw h straight to GLOBAL.
// HARD RULE (empirical, 4 fails / 2 passes): MFMA-derived h must NOT be
// consumed in this kernel -- LN lives in K3 across a kernel boundary.
template <int SC>
__global__ __launch_bounds__(512, 4) void fused_kernel(
    const float* __restrict__ hidden1,
    const f32x4* __restrict__ h2src,    // hidden2 as f32x4
    const unsigned short* __restrict__ W2f,
    const int* __restrict__ node_batch,
    const int* __restrict__ neigh2,
    int* __restrict__ winner,
    float* __restrict__ hout,          // [B][256] raw x@W2 (d_out scratch)
    float* __restrict__ out_tab,       // [N][256]
    int half4, int B, int S_rt)
{
    // ---- copy (first half) + winner blocks ----
    if ((blockIdx.x & 1) == 0) {
        const int tid = (blockIdx.x >> 1) * 512 + threadIdx.x;
        const int stride = COPY_BLOCKS * 512;
        f32x4* dst = (f32x4*)out_tab;
        for (int i = tid; i < half4; i += stride) {
            f32x4 v = __builtin_nontemporal_load(&h2src[i]);
            __builtin_nontemporal_store(v, &dst[i]);
        }
        for (int i = tid; i < B; i += stride) atomicMax(&winner[node_batch[i]], i);
        return;
    }

    // ---- mfma blocks ----
    __shared__ unsigned short xbf[ROWS][KDIM + XBPAD]; // 16.6 KB
    const int t    = threadIdx.x;
    const int lane = t & 63;
    const int w    = t >> 6;           // wave id 0..7
    const int row0 = (blockIdx.x >> 1) * ROWS;

    // stage 1: gather neighbors (mean) + self row -> bf16 LDS
    #pragma unroll
    for (int rr = 0; rr < 2; ++rr) {
        const int r = w + rr * 8;
        int b = row0 + r;
        if (b >= B) b = B - 1;
        const int selfidx = node_batch[b];
        float4 a = make_float4(0.f, 0.f, 0.f, 0.f);
        if constexpr (SC > 0) {
            const int* nb = neigh2 + (size_t)b * SC;
            int idx[SC > 0 ? SC : 1];
            #pragma unroll
            for (int s = 0; s < SC; ++s) idx[s] = nb[s];
            #pragma unroll
            for (int s = 0; s < SC; ++s) {
                float4 v = *(const float4*)&hidden1[(size_t)idx[s] * HDIM + 4 * lane];
                a.x += v.x; a.y += v.y; a.z += v.z; a.w += v.w;
            }
            const float invS = 1.0f / (float)SC;
            a.x *= invS; a.y *= invS; a.z *= invS; a.w *= invS;
        } else {
            const int* nb = neigh2 + (size_t)b * S_rt;
            for (int s = 0; s < S_rt; ++s) {
                float4 v = *(const float4*)&hidden1[(size_t)nb[s] * HDIM + 4 * lane];
                a.x += v.x; a.y += v.y; a.z += v.z; a.w += v.w;
            }
            const float invS = 1.0f / (float)S_rt;
            a.x *= invS; a.y *= invS; a.z *= invS; a.w *= invS;
        }
        float4 sv = *(const float4*)&hidden1[(size_t)selfidx * HDIM + 4 * lane];
        unsigned short pa[4] = { f2bf(a.x), f2bf(a.y), f2bf(a.z), f2bf(a.w) };
        unsigned short ps[4] = { f2bf(sv.x), f2bf(sv.y), f2bf(sv.z), f2bf(sv.w) };
        *(uint2*)&xbf[r][4 * lane]        = *(uint2*)pa;
        *(uint2*)&xbf[r][HDIM + 4 * lane] = *(uint2*)ps;
    }
    __syncthreads();

    // stage 2: MFMA GEMM (H1: std A, std B, m89 D)
    const int arow = lane & 15;
    const int g8   = (lane >> 4) * 8;
    f32x4 acc0 = {0.f, 0.f, 0.f, 0.f};
    f32x4 acc1 = {0.f, 0.f, 0.f, 0.f};
    const unsigned short* bp0 = W2f + ((size_t)(2 * w) * 1024 + lane) * 8;
    const unsigned short* bp1 = W2f + ((size_t)(2 * w + 1) * 1024 + lane) * 8;

    #pragma unroll
    for (int ks = 0; ks < 16; ++ks) {
        bf16x8 af = *(const bf16x8*)&xbf[arow][ks * 32 + g8];
        bf16x8 b0 = *(const bf16x8*)(bp0 + ks * 512);
        bf16x8 b1 = *(const bf16x8*)(bp1 + ks * 512);
        acc0 = __builtin_amdgcn_mfma_f32_16x16x32_bf16(af, b0, acc0, 0, 0, 0);
        acc1 = __builtin_amdgcn_mfma_f32_16x16x32_bf16(af, b1, acc1, 0, 0, 0);
    }

    // raw h -> global (verified transport; D row=(lane>>4)*4+p, col=lane&15)
    #pragma unroll
    for (int p = 0; p < 4; ++p) {
        const int drow = (lane >> 4) * 4 + p;
        const size_t rbase = (size_t)(row0 + drow) * HDIM;
        hout[rbase + 2 * w * 16 + (lane & 15)]       = acc0[p];
        hout[rbase + (2 * w + 1) * 16 + (lane & 15)] = acc1[p];
    }
}

// K3: interleaved. blockIdx%3==0: NONTEMPORAL copy of hidden2 SECOND HALF ->
// out_tab, SKIPPING winner rows (winner[node] >= 0 -> ln writes that row; the
// skip removes the K3-internal write race and ~16 MB of dead stores. Stale
// winner entries for untouched nodes are negative poison -> never skipped).
// Other blocks: bias + ReLU + LayerNorm over h rows (round-6-verified math)
// -> out_h2 + winner scatter to out_tab. Consumes h across a kernel boundary
// (the proven-safe transport).
__global__ __launch_bounds__(512) void ln_copy_kernel(
    float* __restrict__ out_h2,        // [B][256] in: raw h, out: normalized
    float* __restrict__ out_tab,       // [N][256]
    const f32x4* __restrict__ h2src,
    const float* __restrict__ bias2,
    const float* __restrict__ gamma2,
    const float* __restrict__ beta2,
    const int* __restrict__ node_batch,
    const int* __restrict__ winner,
    int half4, int n4, int ncopy, int B)
{
    if (blockIdx.x % 3 == 0) {
        const int tid = (blockIdx.x / 3) * 512 + threadIdx.x;
        const int stride = ncopy * 512;
        f32x4* dst = (f32x4*)out_tab;
        for (int i = half4 + tid; i < n4; i += stride) {
            if (winner[i >> 6] >= 0) continue;     // ln owns this row
            f32x4 v = __builtin_nontemporal_load(&h2src[i]);
            __builtin_nontemporal_store(v, &dst[i]);
        }
        return;
    }

    const int lnid = (blockIdx.x / 3) * 2 + (blockIdx.x % 3) - 1;
    const int lane = threadIdx.x & 63;
    const int row  = lnid * 8 + (threadIdx.x >> 6);
    if (row >= B) return;

    f32x4 hv = __builtin_nontemporal_load(
        (const f32x4*)&out_h2[(size_t)row * HDIM + 4 * lane]);
    float4 bb = *(const float4*)&bias2[4 * lane];
    float4 gg = *(const float4*)&gamma2[4 * lane];
    float4 ee = *(const float4*)&beta2[4 * lane];
    float bbar[4] = {bb.x, bb.y, bb.z, bb.w};
    float gar[4]  = {gg.x, gg.y, gg.z, gg.w};
    float ear[4]  = {ee.x, ee.y, ee.z, ee.w};

    float v[4];
    float s = 0.f, q = 0.f;
    #pragma unroll
    for (int jj = 0; jj < 4; ++jj) {
        float h = fmaxf(hv[jj] + bbar[jj], 0.0f);
        v[jj] = h;
        s += h;
        q += h * h;
    }
    #pragma unroll
    for (int off = 32; off > 0; off >>= 1) {
        s += __shfl_xor(s, off, 64);
        q += __shfl_xor(q, off, 64);
    }
    float mu   = s * (1.0f / (float)HDIM);
    float var  = q * (1.0f / (float)HDIM) - mu * mu;
    float rstd = rsqrtf(var + LN_EPS);

    f32x4 o;
    o[0] = gar[0] * (v[0] - mu) * rstd + ear[0];
    o[1] = gar[1] * (v[1] - mu) * rstd + ear[1];
    o[2] = gar[2] * (v[2] - mu) * rstd + ear[2];
    o[3] = gar[3] * (v[3] - mu) * rstd + ear[3];
    __builtin_nontemporal_store(o, (f32x4*)&out_h2[(size_t)row * HDIM + 4 * lane]);
    int node = node_batch[row];
    if (winner[node] == row)
        __builtin_nontemporal_store(o, (f32x4*)&out_tab[(size_t)node * HDIM + 4 * lane]);
}

extern "C" void kernel_launch(void* const* d_in, const int* in_sizes, int n_in,
                              void* d_out, int out_size, void* d_ws, size_t ws_size,
                              hipStream_t stream) {
    // Inputs (setup_inputs order): 0 feats (unused - layer1 is dead code),
    // 1 hidden1, 2 hidden2, 3 W1, 4 b1, 5 g1, 6 be1 (unused), 7 W2, 8 b2,
    // 9 g2, 10 be2, 11 node_batch, 12 neigh1 (unused), 13 neigh2
    const float* hidden1 = (const float*)d_in[1];
    const float* hidden2 = (const float*)d_in[2];
    const float* W2      = (const float*)d_in[7];
    const float* b2      = (const float*)d_in[8];
    const float* g2      = (const float*)d_in[9];
    const float* be2     = (const float*)d_in[10];
    const int* node_batch = (const int*)d_in[11];
    const int* neigh2     = (const int*)d_in[13];

    const int B  = in_sizes[11];          // 16384
    const int S  = in_sizes[13] / B;      // 10
    const int NH = in_sizes[2];           // N*256 floats
    const int n4 = NH / 4;
    const int half4 = n4 / 2;

    float* out_h2  = (float*)d_out;                       // [B,256]
    float* out_tab = out_h2 + (size_t)B * HDIM;           // [N,256]
    int* winner = (int*)d_ws;                             // N ints at +0
    unsigned short* W2f = (unsigned short*)((char*)d_ws + 512 * 1024);  // 256 KB

    hipLaunchKernelGGL(prep_init_kernel, dim3(64), dim3(256), 0, stream,
                       W2, W2f, winner, node_batch, B);

    const int mfma_blocks = (B + ROWS - 1) / ROWS;        // 1024
    dim3 grid2(2 * ((COPY_BLOCKS > mfma_blocks) ? COPY_BLOCKS : mfma_blocks));
    if (S == 10) {
        hipLaunchKernelGGL((fused_kernel<10>), grid2, dim3(512), 0, stream,
                           hidden1, (const f32x4*)hidden2, W2f,
                           node_batch, neigh2, winner, out_h2, out_tab,
                           half4, B, S);
    } else {
        hipLaunchKernelGGL((fused_kernel<0>), grid2, dim3(512), 0, stream,
                           hidden1, (const f32x4*)hidden2, W2f,
                           node_batch, neigh2, winner, out_h2, out_tab,
                           half4, B, S);
    }

    const int nln   = (B + 7) / 8;                        // 2048 ln blocks
    const int ncopy = (nln + 1) / 2;                      // 1024 copy blocks
    dim3 grid3(3 * ncopy);                                // %3==0 copy, else ln
    hipLaunchKernelGGL(ln_copy_kernel, grid3, dim3(512), 0, stream,
                       out_h2, out_tab, (const f32x4*)hidden2,
                       b2, g2, be2, node_batch, winner,
                       half4, n4, ncopy, B);
}

// Round 15
// 78.002 us; speedup vs baseline: 1.1839x; 1.1839x over previous
//
#include <hip/hip_runtime.h>

#define HDIM 256   // output hidden dim
#define KDIM 512   // 2*HDIM (concat)
#define ROWS 16    // batch rows per mfma block (one MFMA M-tile)
#define XBPAD 8    // xbf row stride 520 shorts (1040 B, 16B-aligned)
#define LN_EPS 1e-5f
#define COPY_BLOCKS 1024

typedef __attribute__((ext_vector_type(8))) short bf16x8;
typedef __attribute__((ext_vector_type(4))) float f32x4;

static __device__ __forceinline__ unsigned short f2bf(float f) {
    union { float f; unsigned u; } v; v.f = f;
    unsigned r = v.u + 0x7FFF + ((v.u >> 16) & 1);   // RNE
    return (unsigned short)(r >> 16);
}
static __device__ __forceinline__ float bf2f(unsigned u16) {
    union { unsigned u; float f; } v; v.u = u16 << 16; return v.f;
}

// K1: pack W2 -> bf16 B-fragments (round-7 probe-verified layout) + winner init.
// fragment tid = ct*1024 + ks*64 + l; elem j of lane l =
//   W2[ks*32 + (l>>4)*8 + j][ct*16 + (l&15)]
__global__ __launch_bounds__(256) void prep_init_kernel(
    const float* __restrict__ W2, unsigned short* __restrict__ W2f,
    int* __restrict__ winner, const int* __restrict__ node_batch, int B)
{
    int tid = blockIdx.x * 256 + threadIdx.x;      // 0..16383
    for (int i = tid; i < B; i += 64 * 256) winner[node_batch[i]] = -1;
    if (tid >= 16 * 16 * 64) return;
    int l  = tid & 63;
    int ks = (tid >> 6) & 15;
    int ct = tid >> 10;
    int col = ct * 16 + (l & 15);
    int k0  = ks * 32 + (l >> 4) * 8;
    unsigned short pk[8];
    #pragma unroll
    for (int j = 0; j < 8; ++j)
        pk[j] = f2bf(W2[(size_t)(k0 + j) * HDIM + col]);
    *(uint4*)&W2f[(size_t)tid * 8] = *(uint4*)pk;
}

// K2: fused producer (R13 structure). Even blocks: NONTEMPORAL full copy
// hidden2 -> out_tab + winner atomicMax. Odd blocks: gather+mean -> bf16 LDS
// -> MFMA (probe-verified H1 config) -> raw h as BF16 to GLOBAL d_ws scratch.
// HARD RULE (empirical, 4 fails / 2 passes): MFMA-derived h must NOT be
// consumed in this kernel -- LN lives in K3 across a kernel boundary.
template <int SC>
__global__ __launch_bounds__(512, 4) void fused_kernel(
    const float* __restrict__ hidden1,
    const f32x4* __restrict__ h2src,    // hidden2 as f32x4
    const unsigned short* __restrict__ W2f,
    const int* __restrict__ node_batch,
    const int* __restrict__ neigh2,
    int* __restrict__ winner,
    unsigned short* __restrict__ hb16, // [B][256] raw x@W2 in bf16 (d_ws)
    float* __restrict__ out_tab,       // [N][256]
    int n4, int B, int S_rt)
{
    // ---- copy + winner blocks ----
    if ((blockIdx.x & 1) == 0) {
        const int tid = (blockIdx.x >> 1) * 512 + threadIdx.x;
        const int stride = COPY_BLOCKS * 512;
        f32x4* dst = (f32x4*)out_tab;
        for (int i = tid; i < n4; i += stride) {
            f32x4 v = __builtin_nontemporal_load(&h2src[i]);
            __builtin_nontemporal_store(v, &dst[i]);
        }
        for (int i = tid; i < B; i += stride) atomicMax(&winner[node_batch[i]], i);
        return;
    }

    // ---- mfma blocks ----
    __shared__ unsigned short xbf[ROWS][KDIM + XBPAD]; // 16.6 KB
    const int t    = threadIdx.x;
    const int lane = t & 63;
    const int w    = t >> 6;           // wave id 0..7
    const int row0 = (blockIdx.x >> 1) * ROWS;

    // stage 1: gather neighbors (mean) + self row -> bf16 LDS
    #pragma unroll
    for (int rr = 0; rr < 2; ++rr) {
        const int r = w + rr * 8;
        int b = row0 + r;
        if (b >= B) b = B - 1;
        const int selfidx = node_batch[b];
        float4 a = make_float4(0.f, 0.f, 0.f, 0.f);
        if constexpr (SC > 0) {
            const int* nb = neigh2 + (size_t)b * SC;
            int idx[SC > 0 ? SC : 1];
            #pragma unroll
            for (int s = 0; s < SC; ++s) idx[s] = nb[s];
            #pragma unroll
            for (int s = 0; s < SC; ++s) {
                float4 v = *(const float4*)&hidden1[(size_t)idx[s] * HDIM + 4 * lane];
                a.x += v.x; a.y += v.y; a.z += v.z; a.w += v.w;
            }
            const float invS = 1.0f / (float)SC;
            a.x *= invS; a.y *= invS; a.z *= invS; a.w *= invS;
        } else {
            const int* nb = neigh2 + (size_t)b * S_rt;
            for (int s = 0; s < S_rt; ++s) {
                float4 v = *(const float4*)&hidden1[(size_t)nb[s] * HDIM + 4 * lane];
                a.x += v.x; a.y += v.y; a.z += v.z; a.w += v.w;
            }
            const float invS = 1.0f / (float)S_rt;
            a.x *= invS; a.y *= invS; a.z *= invS; a.w *= invS;
        }
        float4 sv = *(const float4*)&hidden1[(size_t)selfidx * HDIM + 4 * lane];
        unsigned short pa[4] = { f2bf(a.x), f2bf(a.y), f2bf(a.z), f2bf(a.w) };
        unsigned short ps[4] = { f2bf(sv.x), f2bf(sv.y), f2bf(sv.z), f2bf(sv.w) };
        *(uint2*)&xbf[r][4 * lane]        = *(uint2*)pa;
        *(uint2*)&xbf[r][HDIM + 4 * lane] = *(uint2*)ps;
    }
    __syncthreads();

    // stage 2: MFMA GEMM (H1: std A, std B, m89 D)
    const int arow = lane & 15;
    const int g8   = (lane >> 4) * 8;
    f32x4 acc0 = {0.f, 0.f, 0.f, 0.f};
    f32x4 acc1 = {0.f, 0.f, 0.f, 0.f};
    const unsigned short* bp0 = W2f + ((size_t)(2 * w) * 1024 + lane) * 8;
    const unsigned short* bp1 = W2f + ((size_t)(2 * w + 1) * 1024 + lane) * 8;

    #pragma unroll
    for (int ks = 0; ks < 16; ++ks) {
        bf16x8 af = *(const bf16x8*)&xbf[arow][ks * 32 + g8];
        bf16x8 b0 = *(const bf16x8*)(bp0 + ks * 512);
        bf16x8 b1 = *(const bf16x8*)(bp1 + ks * 512);
        acc0 = __builtin_amdgcn_mfma_f32_16x16x32_bf16(af, b0, acc0, 0, 0, 0);
        acc1 = __builtin_amdgcn_mfma_f32_16x16x32_bf16(af, b1, acc1, 0, 0, 0);
    }

    // raw h (bf16) -> global d_ws (verified transport path, halved bytes;
    // D row=(lane>>4)*4+p, col=lane&15)
    #pragma unroll
    for (int p = 0; p < 4; ++p) {
        const int drow = (lane >> 4) * 4 + p;
        const size_t rbase = (size_t)(row0 + drow) * HDIM;
        hb16[rbase + 2 * w * 16 + (lane & 15)]       = f2bf(acc0[p]);
        hb16[rbase + (2 * w + 1) * 16 + (lane & 15)] = f2bf(acc1[p]);
    }
}

// K3: bias + ReLU + LayerNorm over bf16 h rows -> out_h2 + winner-scatter to
// out_tab. 512 threads = 8 waves = 8 rows/block. Round-6-verified reduce math;
// consumes h across a kernel boundary (the proven-safe transport). h read is
// L2-hot (8.4 MB just written). Final stores nontemporal.
__global__ __launch_bounds__(512) void ln_kernel(
    const unsigned short* __restrict__ hb16,  // [B][256] raw h in bf16
    float* __restrict__ out_h2,        // [B][256] final
    float* __restrict__ out_tab,       // [N][256]
    const float* __restrict__ bias2,
    const float* __restrict__ gamma2,
    const float* __restrict__ beta2,
    const int* __restrict__ node_batch,
    const int* __restrict__ winner,
    int B)
{
    const int lane = threadIdx.x & 63;
    const int row  = blockIdx.x * 8 + (threadIdx.x >> 6);
    if (row >= B) return;

    uint2 hu = *(const uint2*)&hb16[(size_t)row * HDIM + 4 * lane];
    float4 bb = *(const float4*)&bias2[4 * lane];
    float4 gg = *(const float4*)&gamma2[4 * lane];
    float4 ee = *(const float4*)&beta2[4 * lane];
    float bbar[4] = {bb.x, bb.y, bb.z, bb.w};
    float gar[4]  = {gg.x, gg.y, gg.z, gg.w};
    float ear[4]  = {ee.x, ee.y, ee.z, ee.w};
    float hh[4] = { bf2f(hu.x & 0xffffu), bf2f(hu.x >> 16),
                    bf2f(hu.y & 0xffffu), bf2f(hu.y >> 16) };

    float v[4];
    float s = 0.f, q = 0.f;
    #pragma unroll
    for (int jj = 0; jj < 4; ++jj) {
        float h = fmaxf(hh[jj] + bbar[jj], 0.0f);
        v[jj] = h;
        s += h;
        q += h * h;
    }
    #pragma unroll
    for (int off = 32; off > 0; off >>= 1) {
        s += __shfl_xor(s, off, 64);
        q += __shfl_xor(q, off, 64);
    }
    float mu   = s * (1.0f / (float)HDIM);
    float var  = q * (1.0f / (float)HDIM) - mu * mu;
    float rstd = rsqrtf(var + LN_EPS);

    f32x4 o;
    o[0] = gar[0] * (v[0] - mu) * rstd + ear[0];
    o[1] = gar[1] * (v[1] - mu) * rstd + ear[1];
    o[2] = gar[2] * (v[2] - mu) * rstd + ear[2];
    o[3] = gar[3] * (v[3] - mu) * rstd + ear[3];
    __builtin_nontemporal_store(o, (f32x4*)&out_h2[(size_t)row * HDIM + 4 * lane]);
    int node = node_batch[row];
    if (winner[node] == row)
        __builtin_nontemporal_store(o, (f32x4*)&out_tab[(size_t)node * HDIM + 4 * lane]);
}

extern "C" void kernel_launch(void* const* d_in, const int* in_sizes, int n_in,
                              void* d_out, int out_size, void* d_ws, size_t ws_size,
                              hipStream_t stream) {
    // Inputs (setup_inputs order): 0 feats (unused - layer1 is dead code),
    // 1 hidden1, 2 hidden2, 3 W1, 4 b1, 5 g1, 6 be1 (unused), 7 W2, 8 b2,
    // 9 g2, 10 be2, 11 node_batch, 12 neigh1 (unused), 13 neigh2
    const float* hidden1 = (const float*)d_in[1];
    const float* hidden2 = (const float*)d_in[2];
    const float* W2      = (const float*)d_in[7];
    const float* b2      = (const float*)d_in[8];
    const float* g2      = (const float*)d_in[9];
    const float* be2     = (const float*)d_in[10];
    const int* node_batch = (const int*)d_in[11];
    const int* neigh2     = (const int*)d_in[13];

    const int B  = in_sizes[11];          // 16384
    const int S  = in_sizes[13] / B;      // 10
    const int NH = in_sizes[2];           // N*256 floats

    float* out_h2  = (float*)d_out;                       // [B,256]
    float* out_tab = out_h2 + (size_t)B * HDIM;           // [N,256]
    int* winner = (int*)d_ws;                             // N ints at +0
    unsigned short* W2f  = (unsigned short*)((char*)d_ws + 512 * 1024);   // 256 KB
    unsigned short* hb16 = (unsigned short*)((char*)d_ws + 1024 * 1024);  // 8.4 MB

    hipLaunchKernelGGL(prep_init_kernel, dim3(64), dim3(256), 0, stream,
                       W2, W2f, winner, node_batch, B);

    const int mfma_blocks = (B + ROWS - 1) / ROWS;        // 1024
    dim3 grid2(2 * ((COPY_BLOCKS > mfma_blocks) ? COPY_BLOCKS : mfma_blocks));
    if (S == 10) {
        hipLaunchKernelGGL((fused_kernel<10>), grid2, dim3(512), 0, stream,
                           hidden1, (const f32x4*)hidden2, W2f,
                           node_batch, neigh2, winner, hb16, out_tab,
                           NH / 4, B, S);
    } else {
        hipLaunchKernelGGL((fused_kernel<0>), grid2, dim3(512), 0, stream,
                           hidden1, (const f32x4*)hidden2, W2f,
                           node_batch, neigh2, winner, hb16, out_tab,
                           NH / 4, B, S);
    }
    hipLaunchKernelGGL(ln_kernel, dim3((B + 7) / 8), dim3(512), 0, stream,
                       hb16, out_h2, out_tab, b2, g2, be2, node_batch, winner, B);
}

// Round 16
// 77.410 us; speedup vs baseline: 1.1929x; 1.0077x over previous
//
#include <hip/hip_runtime.h>

#define HDIM 256   // output hidden dim
#define KDIM 512   // 2*HDIM (concat)
#define ROWS 16    // batch rows per mfma block (one MFMA M-tile)
#define XBPAD 8    // xbf row stride 520 shorts (1040 B, 16B-aligned)
#define LN_EPS 1e-5f
#define COPY_BLOCKS 1024

typedef __attribute__((ext_vector_type(8))) short bf16x8;
typedef __attribute__((ext_vector_type(4))) float f32x4;

static __device__ __forceinline__ unsigned short f2bf(float f) {
    union { float f; unsigned u; } v; v.f = f;
    unsigned r = v.u + 0x7FFF + ((v.u >> 16) & 1);   // RNE
    return (unsigned short)(r >> 16);
}
static __device__ __forceinline__ float bf2f(unsigned u16) {
    union { unsigned u; float f; } v; v.u = u16 << 16; return v.f;
}

// K1: pack W2 -> bf16 B-fragments (round-7 probe-verified layout) + winner init.
__global__ __launch_bounds__(256) void prep_init_kernel(
    const float* __restrict__ W2, unsigned short* __restrict__ W2f,
    int* __restrict__ winner, const int* __restrict__ node_batch, int B)
{
    int tid = blockIdx.x * 256 + threadIdx.x;      // 0..16383
    for (int i = tid; i < B; i += 64 * 256) winner[node_batch[i]] = -1;
    if (tid >= 16 * 16 * 64) return;
    int l  = tid & 63;
    int ks = (tid >> 6) & 15;
    int ct = tid >> 10;
    int col = ct * 16 + (l & 15);
    int k0  = ks * 32 + (l >> 4) * 8;
    unsigned short pk[8];
    #pragma unroll
    for (int j = 0; j < 8; ++j)
        pk[j] = f2bf(W2[(size_t)(k0 + j) * HDIM + col]);
    *(uint4*)&W2f[(size_t)tid * 8] = *(uint4*)pk;
}

// K2: fused producer. Even blocks: nt copy hidden2 -> out_tab + winner
// atomicMax. Odd blocks: gather (MAX-MLP: all 22 row-loads issued into named
// registers BEFORE any sum -- the R15 profile showed VGPR=36 capped in-flight
// loads at ~8/wave, which was the latency bottleneck) -> bf16 LDS -> MFMA
// (probe-verified H1 config) -> raw h as BF16 to GLOBAL d_ws scratch.
// HARD RULE (empirical, 4 fails / 2 passes): MFMA-derived h must NOT be
// consumed in this kernel -- LN lives in K3 across a kernel boundary.
template <int SC>
__global__ __launch_bounds__(512, 4) void fused_kernel(
    const float* __restrict__ hidden1,
    const f32x4* __restrict__ h2src,    // hidden2 as f32x4
    const unsigned short* __restrict__ W2f,
    const int* __restrict__ node_batch,
    const int* __restrict__ neigh2,
    int* __restrict__ winner,
    unsigned short* __restrict__ hb16, // [B][256] raw x@W2 in bf16 (d_ws)
    float* __restrict__ out_tab,       // [N][256]
    int n4, int B, int S_rt)
{
    // ---- copy + winner blocks ----
    if ((blockIdx.x & 1) == 0) {
        const int tid = (blockIdx.x >> 1) * 512 + threadIdx.x;
        const int stride = COPY_BLOCKS * 512;
        f32x4* dst = (f32x4*)out_tab;
        for (int i = tid; i < n4; i += stride) {
            f32x4 v = __builtin_nontemporal_load(&h2src[i]);
            __builtin_nontemporal_store(v, &dst[i]);
        }
        for (int i = tid; i < B; i += stride) atomicMax(&winner[node_batch[i]], i);
        return;
    }

    // ---- mfma blocks ----
    __shared__ unsigned short xbf[ROWS][KDIM + XBPAD]; // 16.6 KB
    const int t    = threadIdx.x;
    const int lane = t & 63;
    const int w    = t >> 6;           // wave id 0..7
    const int row0 = (blockIdx.x >> 1) * ROWS;

    // stage 1: gather. Phase A: compute all indices. Phase B: issue ALL
    // 2*(SC+1) dwordx4 loads into distinct registers (compile-time indices
    // only -- rule #20). Phase C: sum trees + convert + LDS store.
    if constexpr (SC > 0) {
        int b0 = row0 + w;          if (b0 >= B) b0 = B - 1;
        int b1 = row0 + w + 8;      if (b1 >= B) b1 = B - 1;
        const int* nb0 = neigh2 + (size_t)b0 * SC;
        const int* nb1 = neigh2 + (size_t)b1 * SC;
        int idx0[SC + 1], idx1[SC + 1];
        #pragma unroll
        for (int s = 0; s < SC; ++s) { idx0[s] = nb0[s]; idx1[s] = nb1[s]; }
        idx0[SC] = node_batch[b0];
        idx1[SC] = node_batch[b1];

        float4 v0[SC + 1], v1[SC + 1];
        #pragma unroll
        for (int s = 0; s <= SC; ++s)
            v0[s] = *(const float4*)&hidden1[(size_t)idx0[s] * HDIM + 4 * lane];
        #pragma unroll
        for (int s = 0; s <= SC; ++s)
            v1[s] = *(const float4*)&hidden1[(size_t)idx1[s] * HDIM + 4 * lane];

        const float invS = 1.0f / (float)SC;
        #pragma unroll
        for (int rr = 0; rr < 2; ++rr) {
            const int r = w + rr * 8;
            float4* vv = rr ? v1 : v0;
            float4 a = make_float4(0.f, 0.f, 0.f, 0.f);
            #pragma unroll
            for (int s = 0; s < SC; ++s) {
                a.x += vv[s].x; a.y += vv[s].y; a.z += vv[s].z; a.w += vv[s].w;
            }
            float4 sv = vv[SC];
            unsigned short pa[4] = { f2bf(a.x * invS), f2bf(a.y * invS),
                                     f2bf(a.z * invS), f2bf(a.w * invS) };
            unsigned short ps[4] = { f2bf(sv.x), f2bf(sv.y), f2bf(sv.z), f2bf(sv.w) };
            *(uint2*)&xbf[r][4 * lane]        = *(uint2*)pa;
            *(uint2*)&xbf[r][HDIM + 4 * lane] = *(uint2*)ps;
        }
    } else {
        const float invS = 1.0f / (float)S_rt;
        for (int rr = 0; rr < 2; ++rr) {
            const int r = w + rr * 8;
            int b = row0 + r;
            if (b >= B) b = B - 1;
            const int selfidx = node_batch[b];
            const int* nb = neigh2 + (size_t)b * S_rt;
            float4 a = make_float4(0.f, 0.f, 0.f, 0.f);
            for (int s = 0; s < S_rt; ++s) {
                float4 v = *(const float4*)&hidden1[(size_t)nb[s] * HDIM + 4 * lane];
                a.x += v.x; a.y += v.y; a.z += v.z; a.w += v.w;
            }
            a.x *= invS; a.y *= invS; a.z *= invS; a.w *= invS;
            float4 sv = *(const float4*)&hidden1[(size_t)selfidx * HDIM + 4 * lane];
            unsigned short pa[4] = { f2bf(a.x), f2bf(a.y), f2bf(a.z), f2bf(a.w) };
            unsigned short ps[4] = { f2bf(sv.x), f2bf(sv.y), f2bf(sv.z), f2bf(sv.w) };
            *(uint2*)&xbf[r][4 * lane]        = *(uint2*)pa;
            *(uint2*)&xbf[r][HDIM + 4 * lane] = *(uint2*)ps;
        }
    }
    __syncthreads();

    // stage 2: MFMA GEMM (H1: std A, std B, m89 D)
    const int arow = lane & 15;
    const int g8   = (lane >> 4) * 8;
    f32x4 acc0 = {0.f, 0.f, 0.f, 0.f};
    f32x4 acc1 = {0.f, 0.f, 0.f, 0.f};
    const unsigned short* bp0 = W2f + ((size_t)(2 * w) * 1024 + lane) * 8;
    const unsigned short* bp1 = W2f + ((size_t)(2 * w + 1) * 1024 + lane) * 8;

    #pragma unroll
    for (int ks = 0; ks < 16; ++ks) {
        bf16x8 af = *(const bf16x8*)&xbf[arow][ks * 32 + g8];
        bf16x8 b0 = *(const bf16x8*)(bp0 + ks * 512);
        bf16x8 b1 = *(const bf16x8*)(bp1 + ks * 512);
        acc0 = __builtin_amdgcn_mfma_f32_16x16x32_bf16(af, b0, acc0, 0, 0, 0);
        acc1 = __builtin_amdgcn_mfma_f32_16x16x32_bf16(af, b1, acc1, 0, 0, 0);
    }

    // raw h (bf16) -> global d_ws (verified transport path;
    // D row=(lane>>4)*4+p, col=lane&15)
    #pragma unroll
    for (int p = 0; p < 4; ++p) {
        const int drow = (lane >> 4) * 4 + p;
        const size_t rbase = (size_t)(row0 + drow) * HDIM;
        hb16[rbase + 2 * w * 16 + (lane & 15)]       = f2bf(acc0[p]);
        hb16[rbase + (2 * w + 1) * 16 + (lane & 15)] = f2bf(acc1[p]);
    }
}

// K3: bias + ReLU + LayerNorm over bf16 h rows -> out_h2 + winner-scatter to
// out_tab. 512 threads = 8 rows/block. Consumes h across a kernel boundary
// (the proven-safe transport). Final stores nontemporal.
__global__ __launch_bounds__(512) void ln_kernel(
    const unsigned short* __restrict__ hb16,  // [B][256] raw h in bf16
    float* __restrict__ out_h2,        // [B][256] final
    float* __restrict__ out_tab,       // [N][256]
    const float* __restrict__ bias2,
    const float* __restrict__ gamma2,
    const float* __restrict__ beta2,
    const int* __restrict__ node_batch,
    const int* __restrict__ winner,
    int B)
{
    const int lane = threadIdx.x & 63;
    const int row  = blockIdx.x * 8 + (threadIdx.x >> 6);
    if (row >= B) return;

    uint2 hu = *(const uint2*)&hb16[(size_t)row * HDIM + 4 * lane];
    float4 bb = *(const float4*)&bias2[4 * lane];
    float4 gg = *(const float4*)&gamma2[4 * lane];
    float4 ee = *(const float4*)&beta2[4 * lane];
    float bbar[4] = {bb.x, bb.y, bb.z, bb.w};
    float gar[4]  = {gg.x, gg.y, gg.z, gg.w};
    float ear[4]  = {ee.x, ee.y, ee.z, ee.w};
    float hh[4] = { bf2f(hu.x & 0xffffu), bf2f(hu.x >> 16),
                    bf2f(hu.y & 0xffffu), bf2f(hu.y >> 16) };

    float v[4];
    float s = 0.f, q = 0.f;
    #pragma unroll
    for (int jj = 0; jj < 4; ++jj) {
        float h = fmaxf(hh[jj] + bbar[jj], 0.0f);
        v[jj] = h;
        s += h;
        q += h * h;
    }
    #pragma unroll
    for (int off = 32; off > 0; off >>= 1) {
        s += __shfl_xor(s, off, 64);
        q += __shfl_xor(q, off, 64);
    }
    float mu   = s * (1.0f / (float)HDIM);
    float var  = q * (1.0f / (float)HDIM) - mu * mu;
    float rstd = rsqrtf(var + LN_EPS);

    f32x4 o;
    o[0] = gar[0] * (v[0] - mu) * rstd + ear[0];
    o[1] = gar[1] * (v[1] - mu) * rstd + ear[1];
    o[2] = gar[2] * (v[2] - mu) * rstd + ear[2];
    o[3] = gar[3] * (v[3] - mu) * rstd + ear[3];
    __builtin_nontemporal_store(o, (f32x4*)&out_h2[(size_t)row * HDIM + 4 * lane]);
    int node = node_batch[row];
    if (winner[node] == row)
        __builtin_nontemporal_store(o, (f32x4*)&out_tab[(size_t)node * HDIM + 4 * lane]);
}

extern "C" void kernel_launch(void* const* d_in, const int* in_sizes, int n_in,
                              void* d_out, int out_size, void* d_ws, size_t ws_size,
                              hipStream_t stream) {
    // Inputs (setup_inputs order): 0 feats (unused - layer1 is dead code),
    // 1 hidden1, 2 hidden2, 3 W1, 4 b1, 5 g1, 6 be1 (unused), 7 W2, 8 b2,
    // 9 g2, 10 be2, 11 node_batch, 12 neigh1 (unused), 13 neigh2
    const float* hidden1 = (const float*)d_in[1];
    const float* hidden2 = (const float*)d_in[2];
    const float* W2      = (const float*)d_in[7];
    const float* b2      = (const float*)d_in[8];
    const float* g2      = (const float*)d_in[9];
    const float* be2     = (const float*)d_in[10];
    const int* node_batch = (const int*)d_in[11];
    const int* neigh2     = (const int*)d_in[13];

    const int B  = in_sizes[11];          // 16384
    const int S  = in_sizes[13] / B;      // 10
    const int NH = in_sizes[2];           // N*256 floats

    float* out_h2  = (float*)d_out;                       // [B,256]
    float* out_tab = out_h2 + (size_t)B * HDIM;           // [N,256]
    int* winner = (int*)d_ws;                             // N ints at +0
    unsigned short* W2f  = (unsigned short*)((char*)d_ws + 512 * 1024);   // 256 KB
    unsigned short* hb16 = (unsigned short*)((char*)d_ws + 1024 * 1024);  // 8.4 MB

    hipLaunchKernelGGL(prep_init_kernel, dim3(64), dim3(256), 0, stream,
                       W2, W2f, winner, node_batch, B);

    const int mfma_blocks = (B + ROWS - 1) / ROWS;        // 1024
    dim3 grid2(2 * ((COPY_BLOCKS > mfma_blocks) ? COPY_BLOCKS : mfma_blocks));
    if (S == 10) {
        hipLaunchKernelGGL((fused_kernel<10>), grid2, dim3(512), 0, stream,
                           hidden1, (const f32x4*)hidden2, W2f,
                           node_batch, neigh2, winner, hb16, out_tab,
                           NH / 4, B, S);
    } else {
        hipLaunchKernelGGL((fused_kernel<0>), grid2, dim3(512), 0, stream,
                           hidden1, (const f32x4*)hidden2, W2f,
                           node_batch, neigh2, winner, hb16, out_tab,
                           NH / 4, B, S);
    }
    hipLaunchKernelGGL(ln_kernel, dim3((B + 7) / 8), dim3(512), 0, stream,
                       hb16, out_h2, out_tab, b2, g2, be2, node_batch, winner, B);
}